// Round 1
// baseline (123.050 us; speedup 1.0000x reference)
//
#include <hip/hip_runtime.h>

// DifferentiableRGBtoVel: image (4,3,512,512) fp32, cmap (256,3) fp32, v_i (256) fp32
// out velocities (4,512,512) fp32.
//
// logit_k = -dist_k^2 / (T*ln2)  [exp2 form], computed as A_k·p + B_k + C_p where
//   A_k = 2*c_k*K2, B_k = -|c_k|^2*K2, C_p = -|p|^2*K2, K2 = 1/(T*ln2).
// out = sum_k exp2(logit_k)*v_k / sum_k exp2(logit_k)   (shift C_p cancels; all
// logits <= 0 so no overflow; nearest-color logit always >> fp32 underflow).

#define HWSZ 262144              // 512*512
#define NPIX 1048576             // 4*512*512
#define K2F  144.2695040888963f  // 1/(0.01*ln2)

__global__ __launch_bounds__(256) void rgb2vel_prep(
    const float* __restrict__ cmap, const float* __restrict__ v_i,
    float4* __restrict__ ab, float* __restrict__ vv) {
  int k = threadIdx.x;  // 256 threads, 1 block
  float cx = cmap[k * 3 + 0];
  float cy = cmap[k * 3 + 1];
  float cz = cmap[k * 3 + 2];
  float4 r;
  r.x = 2.0f * K2F * cx;
  r.y = 2.0f * K2F * cy;
  r.z = 2.0f * K2F * cz;
  r.w = -K2F * (cx * cx + cy * cy + cz * cz);
  ab[k] = r;
  vv[k] = v_i[k];
}

__global__ __launch_bounds__(256) void rgb2vel_main(
    const float* __restrict__ img, const float4* __restrict__ ab,
    const float* __restrict__ vv, float* __restrict__ out) {
  int t = blockIdx.x * 256 + threadIdx.x;
  if (t >= NPIX) return;
  int n = t >> 18;           // t / HWSZ
  int hw = t & (HWSZ - 1);   // t % HWSZ
  const float* base = img + (size_t)n * 3 * HWSZ + hw;
  float px = base[0];
  float py = base[HWSZ];
  float pz = base[2 * HWSZ];
  float cp = -K2F * fmaf(px, px, fmaf(py, py, pz * pz));

  float s = 0.0f;
  float sv = 0.0f;
#pragma unroll 16
  for (int k = 0; k < 256; ++k) {
    float4 c = ab[k];  // uniform index -> s_load_dwordx4
    float logit = fmaf(c.x, px, fmaf(c.y, py, fmaf(c.z, pz, c.w))) + cp;
    float w = __builtin_amdgcn_exp2f(logit);  // v_exp_f32
    s += w;
    sv = fmaf(w, vv[k], sv);
  }
  out[t] = sv / s;
}

extern "C" void kernel_launch(void* const* d_in, const int* in_sizes, int n_in,
                              void* d_out, int out_size, void* d_ws, size_t ws_size,
                              hipStream_t stream) {
  const float* image = (const float*)d_in[0];  // (4,3,512,512)
  const float* cmap  = (const float*)d_in[1];  // (256,3)
  const float* v_i   = (const float*)d_in[2];  // (256,)
  float* out = (float*)d_out;                  // (4,512,512)

  float4* ab = (float4*)d_ws;                      // 256 * 16 B
  float*  vv = (float*)((char*)d_ws + 256 * 16);   // 256 * 4 B

  rgb2vel_prep<<<1, 256, 0, stream>>>(cmap, v_i, ab, vv);
  rgb2vel_main<<<NPIX / 256, 256, 0, stream>>>(image, ab, vv, out);
}

// Round 4
// 103.707 us; speedup vs baseline: 1.1865x; 1.1865x over previous
//
#include <hip/hip_runtime.h>

// DifferentiableRGBtoVel: image (4,3,512,512) fp32, cmap (256,3) fp32, v_i (256) fp32
// out velocities (4,512,512) fp32.
//
// logit_k = -dist_k^2/(T*ln2) = A_k·p + B_k + C_p  (exp2 form), A_k=2*K2*c_k,
// B_k=-K2*|c_k|^2, C_p=-K2*|p|^2, K2=1/(0.01*ln2)=144.27. All logits <= 0,
// so no max-subtraction needed; C_p cancels in the softmax ratio.
//
// v4 (bisection): keep the 2-pixel-per-lane packing (v_pk_fma_f32 for the
// logit + accumulate chains) but use the hardware v_exp_f32 per element —
// numerically identical to the round-1 kernel that PASSED (absmax 0.0039).
// v2/v3's polynomial-exp2 + ext_vector bit_cast + *(v2f*) pointer-cast loads
// failed with a bit-identical absmax 1.71 across two different formulations;
// all of those constructs are removed here. Loads/stores are scalar element
// accesses (compiler merges adjacent ones into dwordx2).

typedef float v2f __attribute__((ext_vector_type(2)));

#define HWSZ 262144              // 512*512
#define NPIX 1048576             // 4*512*512
#define K2F  144.2695040888963f  // 1/(0.01*ln2)

__global__ __launch_bounds__(256) void rgb2vel_prep(
    const float* __restrict__ cmap, const float* __restrict__ v_i,
    float4* __restrict__ ab, float* __restrict__ vv) {
  int k = threadIdx.x;  // 256 threads, 1 block
  float cx = cmap[k * 3 + 0];
  float cy = cmap[k * 3 + 1];
  float cz = cmap[k * 3 + 2];
  float4 r;
  r.x = 2.0f * K2F * cx;
  r.y = 2.0f * K2F * cy;
  r.z = 2.0f * K2F * cz;
  r.w = -K2F * (cx * cx + cy * cy + cz * cz);
  ab[k] = r;
  vv[k] = v_i[k];
}

__global__ __launch_bounds__(256) void rgb2vel_main(
    const float* __restrict__ img, const float4* __restrict__ ab,
    const float* __restrict__ vv, float* __restrict__ out) {
  int t = blockIdx.x * 256 + threadIdx.x;  // pair index, [0, NPIX/2)
  int n = t >> 17;                         // image index (131072 pairs/image)
  int hw2 = (t & 131071) << 1;             // first pixel of the pair
  const float* base = img + (size_t)n * 3 * HWSZ + hw2;
  v2f px = {base[0], base[1]};
  v2f py = {base[HWSZ], base[HWSZ + 1]};
  v2f pz = {base[2 * HWSZ], base[2 * HWSZ + 1]};

  // cp = -K2*|p|^2 per pixel (packed)
  v2f mk2 = {-K2F, -K2F};
  v2f cp = __builtin_elementwise_fma(
               px, px, __builtin_elementwise_fma(py, py, pz * pz)) *
           mk2;

  v2f s = {0.0f, 0.0f};
  v2f sv = {0.0f, 0.0f};
#pragma unroll 16
  for (int k = 0; k < 256; ++k) {
    float4 c = ab[k];  // uniform index -> s_load_dwordx4
    v2f cx = {c.x, c.x};
    v2f cy = {c.y, c.y};
    v2f cz = {c.z, c.z};
    v2f cw = {c.w, c.w};
    // logit = A·p + B + cp   (4 pk ops)
    v2f a = __builtin_elementwise_fma(
        cx, px,
        __builtin_elementwise_fma(cy, py,
                                  __builtin_elementwise_fma(cz, pz, cw + cp)));
    // hardware exp2 per element (opaque intrinsic, round-1-verified numerics)
    v2f w;
    w.x = __builtin_amdgcn_exp2f(a.x);
    w.y = __builtin_amdgcn_exp2f(a.y);
    s = s + w;
    float vk = vv[k];  // uniform -> s_load
    v2f vkv = {vk, vk};
    sv = __builtin_elementwise_fma(w, vkv, sv);
  }
  float o0 = sv.x / s.x;
  float o1 = sv.y / s.y;
  size_t o = (size_t)2 * t;
  out[o] = o0;
  out[o + 1] = o1;
}

extern "C" void kernel_launch(void* const* d_in, const int* in_sizes, int n_in,
                              void* d_out, int out_size, void* d_ws, size_t ws_size,
                              hipStream_t stream) {
  const float* image = (const float*)d_in[0];  // (4,3,512,512)
  const float* cmap  = (const float*)d_in[1];  // (256,3)
  const float* v_i   = (const float*)d_in[2];  // (256,)
  float* out = (float*)d_out;                  // (4,512,512)

  float4* ab = (float4*)d_ws;                      // 256 * 16 B
  float*  vv = (float*)((char*)d_ws + 256 * 16);   // 256 * 4 B

  rgb2vel_prep<<<1, 256, 0, stream>>>(cmap, v_i, ab, vv);
  rgb2vel_main<<<NPIX / 2 / 256, 256, 0, stream>>>(image, ab, vv, out);
}